// Round 3
// baseline (541.352 us; speedup 1.0000x reference)
//
#include <hip/hip_runtime.h>
#include <hip/hip_bf16.h>

// MHA: q/k/v proj (gemm_bt) -> flash attention (MFMA, online softmax) -> out proj.
// R3: inputs/output are FP32 (threshold arithmetic proves _any_bf16==False;
// contract says cast per reference dtype = float32). Convert fp32->bf16 in
// registers during staging; MFMA bf16 with fp32 accum; intermediates in d_ws
// as bf16; final output fp32.

typedef __attribute__((ext_vector_type(8))) short bf16x8;   // 8 bf16 = 4 VGPRs (MFMA A/B frag)
typedef __attribute__((ext_vector_type(4))) float f32x4;    // MFMA C/D frag

#define SEQ 4096
#define DM  512

__device__ inline short f2bs(float x) {
    __hip_bfloat16 b = (__hip_bfloat16)x;   // RNE
    return *(short*)&b;
}

__device__ inline float safe_exp(float arg) {
    return __expf(fmaxf(arg, -60.0f));   // never Inf, never exactly 0
}

// C[M,N] = A[M,K] @ W[N,K]^T + bias[N]; A,W,bias fp32; C is OutT (bf16 or fp32).
// 64x64 tile / block, 4 waves, wave = 16 rows x 64 cols, mfma 16x16x32 bf16.
template <typename OutT>
__global__ __launch_bounds__(256) void gemm_bt_bias(
    const float* __restrict__ A,
    const float* __restrict__ W,
    const float* __restrict__ bias,
    OutT* __restrict__ C,
    int M, int N, int K)
{
    __shared__ __align__(16) short As[64 * 32];
    __shared__ __align__(16) short Ws[64 * 32];

    const int bm   = blockIdx.x * 64;
    const int bn   = blockIdx.y * 64;
    const int tid  = threadIdx.x;
    const int wave = tid >> 6;
    const int lane = tid & 63;
    const int quad = lane >> 4;
    const int l16  = lane & 15;

    f32x4 acc[4] = {};

    // staging: 256 threads; each covers 8 fp32 (two float4) per buffer -> 64x32 tile
    const int srow = tid >> 2;
    const int scol = (tid & 3) * 8;

    for (int k0 = 0; k0 < K; k0 += 32) {
        const float4 a0 = *(const float4*)&A[(size_t)(bm + srow) * K + k0 + scol];
        const float4 a1 = *(const float4*)&A[(size_t)(bm + srow) * K + k0 + scol + 4];
        const float4 w0 = *(const float4*)&W[(size_t)(bn + srow) * K + k0 + scol];
        const float4 w1 = *(const float4*)&W[(size_t)(bn + srow) * K + k0 + scol + 4];
        bf16x8 ap, wp;
        ap[0] = f2bs(a0.x); ap[1] = f2bs(a0.y); ap[2] = f2bs(a0.z); ap[3] = f2bs(a0.w);
        ap[4] = f2bs(a1.x); ap[5] = f2bs(a1.y); ap[6] = f2bs(a1.z); ap[7] = f2bs(a1.w);
        wp[0] = f2bs(w0.x); wp[1] = f2bs(w0.y); wp[2] = f2bs(w0.z); wp[3] = f2bs(w0.w);
        wp[4] = f2bs(w1.x); wp[5] = f2bs(w1.y); wp[6] = f2bs(w1.z); wp[7] = f2bs(w1.w);
        *(bf16x8*)&As[srow * 32 + scol] = ap;
        *(bf16x8*)&Ws[srow * 32 + scol] = wp;
        __syncthreads();

        bf16x8 a = *(bf16x8*)&As[(wave * 16 + l16) * 32 + quad * 8];
#pragma unroll
        for (int nt = 0; nt < 4; nt++) {
            bf16x8 b = *(bf16x8*)&Ws[(nt * 16 + l16) * 32 + quad * 8];
            acc[nt] = __builtin_amdgcn_mfma_f32_16x16x32_bf16(a, b, acc[nt], 0, 0, 0);
        }
        __syncthreads();
    }

    // C/D layout (m89-verified): col = lane&15, row = quad*4 + r
#pragma unroll
    for (int nt = 0; nt < 4; nt++) {
        const int col = bn + nt * 16 + l16;
        const float bv = bias[col];
#pragma unroll
        for (int r = 0; r < 4; r++) {
            const int row = bm + wave * 16 + quad * 4 + r;
            C[(size_t)row * N + col] = (OutT)(acc[nt][r] + bv);
        }
    }
}

// Flash attention over projected q/k/v stored bf16 [B*SEQ, 512], head h at cols h*64..h*64+63.
// Block: one (b,h), 64 q-rows. 4 waves, each owns 16 q-rows. KV tiles of 64.
__global__ __launch_bounds__(256) void flash_attn(
    const __hip_bfloat16* __restrict__ Q,
    const __hip_bfloat16* __restrict__ K,
    const __hip_bfloat16* __restrict__ V,
    __hip_bfloat16* __restrict__ O)
{
    __shared__ __align__(16) short Qs[64 * 64];       // [q][d]
    __shared__ __align__(16) short Ks[64 * 64];       // [kv][d]
    __shared__ __align__(16) short Vt[64 * 64];       // [d][kv] (transposed)
    __shared__ __align__(16) short Ps[4][16 * 64];    // per-wave P strip [q_local][kv]

    const int q0 = blockIdx.x * 64;
    const int bh = blockIdx.y;
    const int b  = bh >> 3;
    const int h  = bh & 7;

    const int tid  = threadIdx.x;
    const int wave = tid >> 6;
    const int lane = tid & 63;
    const int quad = lane >> 4;
    const int l16  = lane & 15;

    const __hip_bfloat16* Qb = Q + (size_t)b * SEQ * DM + h * 64;
    const __hip_bfloat16* Kb = K + (size_t)b * SEQ * DM + h * 64;
    const __hip_bfloat16* Vb = V + (size_t)b * SEQ * DM + h * 64;
    __hip_bfloat16*       Ob = O + (size_t)b * SEQ * DM + h * 64;

    // Q tile load (once): 64x64
    for (int i = tid; i < 512; i += 256) {
        int r = i >> 3, c8 = (i & 7) * 8;
        *(bf16x8*)&Qs[r * 64 + c8] = *(const bf16x8*)&Qb[(size_t)(q0 + r) * DM + c8];
    }

    float m_run = -3.0e38f;           // wave-global running max
    float l_r[4] = {0.f, 0.f, 0.f, 0.f};
    f32x4 oacc[4] = {};

    for (int kv0 = 0; kv0 < SEQ; kv0 += 64) {
        __syncthreads();  // prev iter done reading Ks/Vt (covers Qs staging on iter 0)

        for (int i = tid; i < 512; i += 256) {
            int r = i >> 3, c8 = (i & 7) * 8;
            *(bf16x8*)&Ks[r * 64 + c8] = *(const bf16x8*)&Kb[(size_t)(kv0 + r) * DM + c8];
            bf16x8 v = *(const bf16x8*)&Vb[(size_t)(kv0 + r) * DM + c8];
#pragma unroll
            for (int j = 0; j < 8; j++) Vt[(c8 + j) * 64 + r] = v[j];
        }
        __syncthreads();

        // S = Q K^T  (16 q-rows x 64 kv per wave)
        f32x4 s[4] = {};
#pragma unroll
        for (int ks = 0; ks < 2; ks++) {
            bf16x8 a = *(bf16x8*)&Qs[(wave * 16 + l16) * 64 + ks * 32 + quad * 8];
#pragma unroll
            for (int nt = 0; nt < 4; nt++) {
                bf16x8 bf = *(bf16x8*)&Ks[(nt * 16 + l16) * 64 + ks * 32 + quad * 8];
                s[nt] = __builtin_amdgcn_mfma_f32_16x16x32_bf16(a, bf, s[nt], 0, 0, 0);
            }
        }
#pragma unroll
        for (int nt = 0; nt < 4; nt++)
#pragma unroll
            for (int r = 0; r < 4; r++) s[nt][r] *= 0.125f;  // 1/sqrt(64)

        // wave-global tile max: valid upper bound for every row regardless of layout
        float mx = s[0][0];
#pragma unroll
        for (int nt = 0; nt < 4; nt++)
#pragma unroll
            for (int r = 0; r < 4; r++) mx = fmaxf(mx, s[nt][r]);
#pragma unroll
        for (int off = 1; off < 64; off <<= 1)
            mx = fmaxf(mx, __shfl_xor(mx, off, 64));

        const float mnew  = fmaxf(m_run, mx);
        const float alpha = safe_exp(m_run - mnew);
        m_run = mnew;

        float rsum[4] = {0.f, 0.f, 0.f, 0.f};
#pragma unroll
        for (int nt = 0; nt < 4; nt++) {
#pragma unroll
            for (int r = 0; r < 4; r++) {
                float p = safe_exp(s[nt][r] - mnew);   // in (0, 1]
                rsum[r] += p;
                Ps[wave][(quad * 4 + r) * 64 + nt * 16 + l16] = f2bs(p);
            }
        }

        // per-row sum over the 16 lanes sharing row quad*4+r (xor bits 0..3)
#pragma unroll
        for (int r = 0; r < 4; r++) {
#pragma unroll
            for (int off = 1; off < 16; off <<= 1)
                rsum[r] += __shfl_xor(rsum[r], off, 64);
            l_r[r] = alpha * l_r[r] + rsum[r];
        }
#pragma unroll
        for (int dt = 0; dt < 4; dt++)
#pragma unroll
            for (int r = 0; r < 4; r++) oacc[dt][r] *= alpha;

        __syncthreads();  // Ps writes visible before A-frag reads

        // O += P @ V
#pragma unroll
        for (int ks = 0; ks < 2; ks++) {
            bf16x8 a = *(bf16x8*)&Ps[wave][l16 * 64 + ks * 32 + quad * 8];
#pragma unroll
            for (int dt = 0; dt < 4; dt++) {
                bf16x8 bf = *(bf16x8*)&Vt[(dt * 16 + l16) * 64 + ks * 32 + quad * 8];
                oacc[dt] = __builtin_amdgcn_mfma_f32_16x16x32_bf16(a, bf, oacc[dt], 0, 0, 0);
            }
        }
    }

    // epilogue: O / l   (l > 0 guaranteed by safe_exp)
#pragma unroll
    for (int dt = 0; dt < 4; dt++) {
#pragma unroll
        for (int r = 0; r < 4; r++) {
            const int row = q0 + wave * 16 + quad * 4 + r;
            const float inv = 1.0f / l_r[r];
            Ob[(size_t)row * DM + dt * 16 + l16] =
                (__hip_bfloat16)(oacc[dt][r] * inv);
        }
    }
}

// Final projection: A is bf16 (o_ws), W/bias fp32, C fp32.
__global__ __launch_bounds__(256) void gemm_bt_bias_bf16a(
    const __hip_bfloat16* __restrict__ A,
    const float* __restrict__ W,
    const float* __restrict__ bias,
    float* __restrict__ C,
    int M, int N, int K)
{
    __shared__ __align__(16) short As[64 * 32];
    __shared__ __align__(16) short Ws[64 * 32];

    const int bm   = blockIdx.x * 64;
    const int bn   = blockIdx.y * 64;
    const int tid  = threadIdx.x;
    const int wave = tid >> 6;
    const int lane = tid & 63;
    const int quad = lane >> 4;
    const int l16  = lane & 15;

    f32x4 acc[4] = {};

    const int srow = tid >> 2;
    const int scol = (tid & 3) * 8;

    for (int k0 = 0; k0 < K; k0 += 32) {
        *(bf16x8*)&As[srow * 32 + scol] =
            *(const bf16x8*)&A[(size_t)(bm + srow) * K + k0 + scol];
        const float4 w0 = *(const float4*)&W[(size_t)(bn + srow) * K + k0 + scol];
        const float4 w1 = *(const float4*)&W[(size_t)(bn + srow) * K + k0 + scol + 4];
        bf16x8 wp;
        wp[0] = f2bs(w0.x); wp[1] = f2bs(w0.y); wp[2] = f2bs(w0.z); wp[3] = f2bs(w0.w);
        wp[4] = f2bs(w1.x); wp[5] = f2bs(w1.y); wp[6] = f2bs(w1.z); wp[7] = f2bs(w1.w);
        *(bf16x8*)&Ws[srow * 32 + scol] = wp;
        __syncthreads();

        bf16x8 a = *(bf16x8*)&As[(wave * 16 + l16) * 32 + quad * 8];
#pragma unroll
        for (int nt = 0; nt < 4; nt++) {
            bf16x8 b = *(bf16x8*)&Ws[(nt * 16 + l16) * 32 + quad * 8];
            acc[nt] = __builtin_amdgcn_mfma_f32_16x16x32_bf16(a, b, acc[nt], 0, 0, 0);
        }
        __syncthreads();
    }

#pragma unroll
    for (int nt = 0; nt < 4; nt++) {
        const int col = bn + nt * 16 + l16;
        const float bv = bias[col];
#pragma unroll
        for (int r = 0; r < 4; r++) {
            const int row = bm + wave * 16 + quad * 4 + r;
            C[(size_t)row * N + col] = acc[nt][r] + bv;
        }
    }
}

extern "C" void kernel_launch(void* const* d_in, const int* in_sizes, int n_in,
                              void* d_out, int out_size, void* d_ws, size_t ws_size,
                              hipStream_t stream) {
    const float* queries = (const float*)d_in[0];
    const float* keys    = (const float*)d_in[1];
    const float* values  = (const float*)d_in[2];
    const float* Wq = (const float*)d_in[3];
    const float* bq = (const float*)d_in[4];
    const float* Wk = (const float*)d_in[5];
    const float* bk = (const float*)d_in[6];
    const float* Wv = (const float*)d_in[7];
    const float* bv = (const float*)d_in[8];
    const float* Wo = (const float*)d_in[9];
    const float* bo = (const float*)d_in[10];
    float* out = (float*)d_out;

    const size_t MS = (size_t)2 * SEQ * DM;  // elems per bf16 intermediate buffer
    __hip_bfloat16* q_ws = (__hip_bfloat16*)d_ws;
    __hip_bfloat16* k_ws = q_ws + MS;
    __hip_bfloat16* v_ws = k_ws + MS;
    __hip_bfloat16* o_ws = v_ws + MS;

    dim3 blk(256);
    dim3 gp(128, 8);   // 8192/64 x 512/64

    gemm_bt_bias<__hip_bfloat16><<<gp, blk, 0, stream>>>(queries, Wq, bq, q_ws, 2 * SEQ, DM, DM);
    gemm_bt_bias<__hip_bfloat16><<<gp, blk, 0, stream>>>(keys,    Wk, bk, k_ws, 2 * SEQ, DM, DM);
    gemm_bt_bias<__hip_bfloat16><<<gp, blk, 0, stream>>>(values,  Wv, bv, v_ws, 2 * SEQ, DM, DM);

    flash_attn<<<dim3(64, 16), blk, 0, stream>>>(q_ws, k_ws, v_ws, o_ws);

    gemm_bt_bias_bf16a<<<gp, blk, 0, stream>>>(o_ws, Wo, bo, out, 2 * SEQ, DM, DM);
}

// Round 4
// 363.488 us; speedup vs baseline: 1.4893x; 1.4893x over previous
//
#include <hip/hip_runtime.h>
#include <hip/hip_bf16.h>

// MHA: fused qkv proj (V written transposed per-head) -> flash attention
// (padded LDS, register prefetch, no in-kernel transpose) -> out proj.
// R4: attacks flash's 1.3e8 LDS bank conflicts + latency-bound structure.

typedef __attribute__((ext_vector_type(8))) short bf16x8;   // 8 bf16 (MFMA A/B frag)
typedef __attribute__((ext_vector_type(4))) float f32x4;    // MFMA C/D frag

#define SEQ  4096
#define DM   512
#define FPAD 72    // flash LDS row stride (shorts): 144B rows -> conflict-free b128 frag reads

__device__ inline short f2bs(float x) {
    __hip_bfloat16 b = (__hip_bfloat16)x;   // RNE
    return *(short*)&b;
}

__device__ inline float safe_exp(float arg) {
    return __expf(fmaxf(arg, -60.0f));   // never Inf, never exactly 0
}

// Fused QKV projection. z = blockIdx.z selects stream:
//   z=0: Q = (x@Wq^T + bq) * 0.125  -> row-major bf16 [8192][512] (1/sqrt(dk) folded, exact)
//   z=1: K                          -> row-major bf16 [8192][512]
//   z=2: V                          -> transposed per-head bf16: out[(b*512+col)*4096 + seq]
// 64x64 tile, 4 waves, mfma 16x16x32 bf16, register prefetch of next k-chunk.
__global__ __launch_bounds__(256) void qkv_proj(
    const float* __restrict__ Xq, const float* __restrict__ Xk, const float* __restrict__ Xv,
    const float* __restrict__ Wq, const float* __restrict__ Wk, const float* __restrict__ Wv,
    const float* __restrict__ bq, const float* __restrict__ bk, const float* __restrict__ bv,
    __hip_bfloat16* __restrict__ Oq, __hip_bfloat16* __restrict__ Ok,
    __hip_bfloat16* __restrict__ Ovt)
{
    const int z = blockIdx.z;
    const float* A    = (z == 0) ? Xq : (z == 1) ? Xk : Xv;
    const float* W    = (z == 0) ? Wq : (z == 1) ? Wk : Wv;
    const float* bias = (z == 0) ? bq : (z == 1) ? bk : bv;
    const float scale = (z == 0) ? 0.125f : 1.0f;

    __shared__ __align__(16) short As[64 * 32];   // 64B rows: bank-conflict-free (verified arithmetic)
    __shared__ __align__(16) short Ws[64 * 32];

    const int bm   = blockIdx.x * 64;
    const int bn   = blockIdx.y * 64;
    const int tid  = threadIdx.x;
    const int wave = tid >> 6;
    const int lane = tid & 63;
    const int quad = lane >> 4;
    const int l16  = lane & 15;

    const int srow = tid >> 2;
    const int scol = (tid & 3) * 8;

    f32x4 acc[4] = {};

    // prefetch k-chunk 0
    float4 a0 = *(const float4*)&A[(size_t)(bm + srow) * DM + scol];
    float4 a1 = *(const float4*)&A[(size_t)(bm + srow) * DM + scol + 4];
    float4 w0 = *(const float4*)&W[(size_t)(bn + srow) * DM + scol];
    float4 w1 = *(const float4*)&W[(size_t)(bn + srow) * DM + scol + 4];

    for (int k0 = 0; k0 < DM; k0 += 32) {
        bf16x8 ap, wp;
        ap[0] = f2bs(a0.x); ap[1] = f2bs(a0.y); ap[2] = f2bs(a0.z); ap[3] = f2bs(a0.w);
        ap[4] = f2bs(a1.x); ap[5] = f2bs(a1.y); ap[6] = f2bs(a1.z); ap[7] = f2bs(a1.w);
        wp[0] = f2bs(w0.x); wp[1] = f2bs(w0.y); wp[2] = f2bs(w0.z); wp[3] = f2bs(w0.w);
        wp[4] = f2bs(w1.x); wp[5] = f2bs(w1.y); wp[6] = f2bs(w1.z); wp[7] = f2bs(w1.w);

        __syncthreads();   // prev iter's frag reads done
        *(bf16x8*)&As[srow * 32 + scol] = ap;
        *(bf16x8*)&Ws[srow * 32 + scol] = wp;
        __syncthreads();

        if (k0 + 32 < DM) {   // prefetch next chunk; in flight during MFMAs
            a0 = *(const float4*)&A[(size_t)(bm + srow) * DM + k0 + 32 + scol];
            a1 = *(const float4*)&A[(size_t)(bm + srow) * DM + k0 + 32 + scol + 4];
            w0 = *(const float4*)&W[(size_t)(bn + srow) * DM + k0 + 32 + scol];
            w1 = *(const float4*)&W[(size_t)(bn + srow) * DM + k0 + 32 + scol + 4];
        }

        bf16x8 a = *(bf16x8*)&As[(wave * 16 + l16) * 32 + quad * 8];
#pragma unroll
        for (int nt = 0; nt < 4; nt++) {
            bf16x8 b = *(bf16x8*)&Ws[(nt * 16 + l16) * 32 + quad * 8];
            acc[nt] = __builtin_amdgcn_mfma_f32_16x16x32_bf16(a, b, acc[nt], 0, 0, 0);
        }
    }

    // C/D layout: col = lane&15, row = quad*4 + r
    if (z == 2) {
        // transposed per-head store: 4 consecutive seq values -> one ushort4
        const int row0 = bm + wave * 16 + quad * 4;
        const int b    = row0 >> 12;
        const int seq0 = row0 & 4095;
#pragma unroll
        for (int nt = 0; nt < 4; nt++) {
            const int col = bn + nt * 16 + l16;
            const float bv_ = bias[col];
            ushort4 pk;
            pk.x = (unsigned short)f2bs(acc[nt][0] + bv_);
            pk.y = (unsigned short)f2bs(acc[nt][1] + bv_);
            pk.z = (unsigned short)f2bs(acc[nt][2] + bv_);
            pk.w = (unsigned short)f2bs(acc[nt][3] + bv_);
            *(ushort4*)&((unsigned short*)Ovt)[((size_t)(b * 512 + col)) * 4096 + seq0] = pk;
        }
    } else {
        __hip_bfloat16* C = (z == 0) ? Oq : Ok;
#pragma unroll
        for (int nt = 0; nt < 4; nt++) {
            const int col = bn + nt * 16 + l16;
            const float bv_ = bias[col];
#pragma unroll
            for (int r = 0; r < 4; r++) {
                const int row = bm + wave * 16 + quad * 4 + r;
                C[(size_t)row * DM + col] = (__hip_bfloat16)((acc[nt][r] + bv_) * scale);
            }
        }
    }
}

// Flash attention. Q pre-scaled by 1/sqrt(dk). V supplied transposed per-head [bh][64][SEQ].
// Block: one (bh, 64 q-rows); 4 waves x 16 q-rows; KV tiles of 64 with register prefetch.
__global__ __launch_bounds__(256) void flash_attn(
    const __hip_bfloat16* __restrict__ Q,
    const __hip_bfloat16* __restrict__ K,
    const __hip_bfloat16* __restrict__ Vt,
    __hip_bfloat16* __restrict__ O)
{
    __shared__ __align__(16) short Qs[64 * FPAD];
    __shared__ __align__(16) short Ks[64 * FPAD];
    __shared__ __align__(16) short Vs[64 * FPAD];      // [dv][kv], loaded pre-transposed
    __shared__ __align__(16) short Ps[4][16 * FPAD];   // per-wave P strip

    const int q0 = blockIdx.x * 64;
    const int bh = blockIdx.y;

    const int tid  = threadIdx.x;
    const int wave = tid >> 6;
    const int lane = tid & 63;
    const int quad = lane >> 4;
    const int l16  = lane & 15;

    const __hip_bfloat16* Qb = Q + (size_t)(bh >> 3) * SEQ * DM + (bh & 7) * 64;
    const __hip_bfloat16* Kb = K + (size_t)(bh >> 3) * SEQ * DM + (bh & 7) * 64;
    const __hip_bfloat16* Vb = Vt + (size_t)bh * 64 * SEQ;
    __hip_bfloat16*       Ob = O + (size_t)(bh >> 3) * SEQ * DM + (bh & 7) * 64;

    const int r0 = tid >> 3;        // 0..31 (thread covers rows r0 and r0+32)
    const int c8 = (tid & 7) * 8;

    // Q stage (once), padded rows
    *(bf16x8*)&Qs[r0 * FPAD + c8] =
        *(const bf16x8*)&Qb[(size_t)(q0 + r0) * DM + c8];
    *(bf16x8*)&Qs[(r0 + 32) * FPAD + c8] =
        *(const bf16x8*)&Qb[(size_t)(q0 + r0 + 32) * DM + c8];

    // prefetch kv tile 0
    bf16x8 kp0 = *(const bf16x8*)&Kb[(size_t)r0 * DM + c8];
    bf16x8 kp1 = *(const bf16x8*)&Kb[(size_t)(r0 + 32) * DM + c8];
    bf16x8 vp0 = *(const bf16x8*)&Vb[(size_t)r0 * SEQ + c8];
    bf16x8 vp1 = *(const bf16x8*)&Vb[(size_t)(r0 + 32) * SEQ + c8];

    float m_run = -3.0e38f;
    float l_r[4] = {0.f, 0.f, 0.f, 0.f};
    f32x4 oacc[4] = {};

    for (int kv0 = 0; kv0 < SEQ; kv0 += 64) {
        __syncthreads();   // prev PV done reading Ks/Vs (iter 0: also orders Qs stage)
        *(bf16x8*)&Ks[r0 * FPAD + c8] = kp0;
        *(bf16x8*)&Ks[(r0 + 32) * FPAD + c8] = kp1;
        *(bf16x8*)&Vs[r0 * FPAD + c8] = vp0;
        *(bf16x8*)&Vs[(r0 + 32) * FPAD + c8] = vp1;
        __syncthreads();

        if (kv0 + 64 < SEQ) {   // prefetch next tile; overlaps softmax + PV
            kp0 = *(const bf16x8*)&Kb[(size_t)(kv0 + 64 + r0) * DM + c8];
            kp1 = *(const bf16x8*)&Kb[(size_t)(kv0 + 96 + r0) * DM + c8];
            vp0 = *(const bf16x8*)&Vb[(size_t)r0 * SEQ + kv0 + 64 + c8];
            vp1 = *(const bf16x8*)&Vb[(size_t)(r0 + 32) * SEQ + kv0 + 64 + c8];
        }

        // S = Q K^T (Q pre-scaled)
        f32x4 s[4] = {};
#pragma unroll
        for (int ks = 0; ks < 2; ks++) {
            bf16x8 a = *(bf16x8*)&Qs[(wave * 16 + l16) * FPAD + ks * 32 + quad * 8];
#pragma unroll
            for (int nt = 0; nt < 4; nt++) {
                bf16x8 b = *(bf16x8*)&Ks[(nt * 16 + l16) * FPAD + ks * 32 + quad * 8];
                s[nt] = __builtin_amdgcn_mfma_f32_16x16x32_bf16(a, b, s[nt], 0, 0, 0);
            }
        }

        // wave-global running max (upper-bounds every row; exact for online softmax)
        float mx = s[0][0];
#pragma unroll
        for (int nt = 0; nt < 4; nt++)
#pragma unroll
            for (int r = 0; r < 4; r++) mx = fmaxf(mx, s[nt][r]);
#pragma unroll
        for (int off = 1; off < 64; off <<= 1)
            mx = fmaxf(mx, __shfl_xor(mx, off, 64));

        const float mnew  = fmaxf(m_run, mx);
        const float alpha = safe_exp(m_run - mnew);
        m_run = mnew;

        float rsum[4] = {0.f, 0.f, 0.f, 0.f};
#pragma unroll
        for (int nt = 0; nt < 4; nt++) {
#pragma unroll
            for (int r = 0; r < 4; r++) {
                float p = safe_exp(s[nt][r] - mnew);
                rsum[r] += p;
                Ps[wave][(quad * 4 + r) * FPAD + nt * 16 + l16] = f2bs(p);
            }
        }

#pragma unroll
        for (int r = 0; r < 4; r++) {
#pragma unroll
            for (int off = 1; off < 16; off <<= 1)
                rsum[r] += __shfl_xor(rsum[r], off, 64);
            l_r[r] = alpha * l_r[r] + rsum[r];
        }
#pragma unroll
        for (int dt = 0; dt < 4; dt++)
#pragma unroll
            for (int r = 0; r < 4; r++) oacc[dt][r] *= alpha;

        __syncthreads();   // Ps visible

        // O += P @ V  (B-frag from pre-transposed Vs: contiguous, padded)
#pragma unroll
        for (int ks = 0; ks < 2; ks++) {
            bf16x8 a = *(bf16x8*)&Ps[wave][l16 * FPAD + ks * 32 + quad * 8];
#pragma unroll
            for (int dt = 0; dt < 4; dt++) {
                bf16x8 b = *(bf16x8*)&Vs[(dt * 16 + l16) * FPAD + ks * 32 + quad * 8];
                oacc[dt] = __builtin_amdgcn_mfma_f32_16x16x32_bf16(a, b, oacc[dt], 0, 0, 0);
            }
        }
    }

    // epilogue: O / l
#pragma unroll
    for (int dt = 0; dt < 4; dt++) {
#pragma unroll
        for (int r = 0; r < 4; r++) {
            const int row = q0 + wave * 16 + quad * 4 + r;
            Ob[(size_t)row * DM + dt * 16 + l16] =
                (__hip_bfloat16)(oacc[dt][r] / l_r[r]);
        }
    }
}

// Output projection: A bf16 [8192][512], W/bias fp32, C fp32. Register prefetch.
__global__ __launch_bounds__(256) void out_proj(
    const __hip_bfloat16* __restrict__ A,
    const float* __restrict__ W,
    const float* __restrict__ bias,
    float* __restrict__ C)
{
    __shared__ __align__(16) short As[64 * 32];
    __shared__ __align__(16) short Ws[64 * 32];

    const int bm   = blockIdx.x * 64;
    const int bn   = blockIdx.y * 64;
    const int tid  = threadIdx.x;
    const int wave = tid >> 6;
    const int lane = tid & 63;
    const int quad = lane >> 4;
    const int l16  = lane & 15;

    const int srow = tid >> 2;
    const int scol = (tid & 3) * 8;

    f32x4 acc[4] = {};

    bf16x8 ap = *(const bf16x8*)&A[(size_t)(bm + srow) * DM + scol];
    float4 w0 = *(const float4*)&W[(size_t)(bn + srow) * DM + scol];
    float4 w1 = *(const float4*)&W[(size_t)(bn + srow) * DM + scol + 4];

    for (int k0 = 0; k0 < DM; k0 += 32) {
        bf16x8 wp;
        wp[0] = f2bs(w0.x); wp[1] = f2bs(w0.y); wp[2] = f2bs(w0.z); wp[3] = f2bs(w0.w);
        wp[4] = f2bs(w1.x); wp[5] = f2bs(w1.y); wp[6] = f2bs(w1.z); wp[7] = f2bs(w1.w);

        __syncthreads();
        *(bf16x8*)&As[srow * 32 + scol] = ap;
        *(bf16x8*)&Ws[srow * 32 + scol] = wp;
        __syncthreads();

        if (k0 + 32 < DM) {
            ap = *(const bf16x8*)&A[(size_t)(bm + srow) * DM + k0 + 32 + scol];
            w0 = *(const float4*)&W[(size_t)(bn + srow) * DM + k0 + 32 + scol];
            w1 = *(const float4*)&W[(size_t)(bn + srow) * DM + k0 + 32 + scol + 4];
        }

        bf16x8 a = *(bf16x8*)&As[(wave * 16 + l16) * 32 + quad * 8];
#pragma unroll
        for (int nt = 0; nt < 4; nt++) {
            bf16x8 b = *(bf16x8*)&Ws[(nt * 16 + l16) * 32 + quad * 8];
            acc[nt] = __builtin_amdgcn_mfma_f32_16x16x32_bf16(a, b, acc[nt], 0, 0, 0);
        }
    }

#pragma unroll
    for (int nt = 0; nt < 4; nt++) {
        const int col = bn + nt * 16 + l16;
        const float bv_ = bias[col];
#pragma unroll
        for (int r = 0; r < 4; r++) {
            const int row = bm + wave * 16 + quad * 4 + r;
            C[(size_t)row * DM + col] = acc[nt][r] + bv_;
        }
    }
}

extern "C" void kernel_launch(void* const* d_in, const int* in_sizes, int n_in,
                              void* d_out, int out_size, void* d_ws, size_t ws_size,
                              hipStream_t stream) {
    const float* queries = (const float*)d_in[0];
    const float* keys    = (const float*)d_in[1];
    const float* values  = (const float*)d_in[2];
    const float* Wq = (const float*)d_in[3];
    const float* bq = (const float*)d_in[4];
    const float* Wk = (const float*)d_in[5];
    const float* bk = (const float*)d_in[6];
    const float* Wv = (const float*)d_in[7];
    const float* bv = (const float*)d_in[8];
    const float* Wo = (const float*)d_in[9];
    const float* bo = (const float*)d_in[10];
    float* out = (float*)d_out;

    const size_t MS = (size_t)2 * SEQ * DM;
    __hip_bfloat16* q_ws  = (__hip_bfloat16*)d_ws;
    __hip_bfloat16* k_ws  = q_ws + MS;
    __hip_bfloat16* vt_ws = k_ws + MS;    // [16][64][4096]
    __hip_bfloat16* o_ws  = vt_ws + MS;

    dim3 blk(256);

    qkv_proj<<<dim3(128, 8, 3), blk, 0, stream>>>(
        queries, keys, values, Wq, Wk, Wv, bq, bk, bv, q_ws, k_ws, vt_ws);

    flash_attn<<<dim3(64, 16), blk, 0, stream>>>(q_ws, k_ws, vt_ws, o_ws);

    out_proj<<<dim3(128, 8), blk, 0, stream>>>(o_ws, Wo, bo, out);
}

// Round 5
// 318.064 us; speedup vs baseline: 1.7020x; 1.1428x over previous
//
#include <hip/hip_runtime.h>
#include <hip/hip_bf16.h>

// MHA: fused qkv proj (V written transposed per-head) -> flash attention
// (padded LDS, register prefetch) -> out proj.
// R5: flash de-overheading — (1) drop the Ps barrier (per-wave scratch needs
// no __syncthreads; compiler orders same-wave DS ops via lgkmcnt), (2) softmax
// denominator via ones-MFMA into a 5th accumulator tile (row mapping matches
// oacc) instead of 32 shuffle+add ops per iter.

typedef __attribute__((ext_vector_type(8))) short bf16x8;   // 8 bf16 (MFMA A/B frag)
typedef __attribute__((ext_vector_type(4))) float f32x4;    // MFMA C/D frag

#define SEQ  4096
#define DM   512
#define FPAD 72    // flash LDS row stride (shorts): 144B rows -> conflict-free b128 frag reads

__device__ inline short f2bs(float x) {
    __hip_bfloat16 b = (__hip_bfloat16)x;   // RNE
    return *(short*)&b;
}

__device__ inline float safe_exp(float arg) {
    return __expf(fmaxf(arg, -60.0f));   // never Inf, never exactly 0
}

// Fused QKV projection. z = blockIdx.z selects stream:
//   z=0: Q = (x@Wq^T + bq) * 0.125  -> row-major bf16 [8192][512] (1/sqrt(dk) folded)
//   z=1: K                          -> row-major bf16 [8192][512]
//   z=2: V                          -> transposed per-head: out[(b*512+col)*4096 + seq]
__global__ __launch_bounds__(256) void qkv_proj(
    const float* __restrict__ Xq, const float* __restrict__ Xk, const float* __restrict__ Xv,
    const float* __restrict__ Wq, const float* __restrict__ Wk, const float* __restrict__ Wv,
    const float* __restrict__ bq, const float* __restrict__ bk, const float* __restrict__ bv,
    __hip_bfloat16* __restrict__ Oq, __hip_bfloat16* __restrict__ Ok,
    __hip_bfloat16* __restrict__ Ovt)
{
    const int z = blockIdx.z;
    const float* A    = (z == 0) ? Xq : (z == 1) ? Xk : Xv;
    const float* W    = (z == 0) ? Wq : (z == 1) ? Wk : Wv;
    const float* bias = (z == 0) ? bq : (z == 1) ? bk : bv;
    const float scale = (z == 0) ? 0.125f : 1.0f;

    __shared__ __align__(16) short As[64 * 32];   // 64B rows: conflict-free
    __shared__ __align__(16) short Ws[64 * 32];

    const int bm   = blockIdx.x * 64;
    const int bn   = blockIdx.y * 64;
    const int tid  = threadIdx.x;
    const int wave = tid >> 6;
    const int lane = tid & 63;
    const int quad = lane >> 4;
    const int l16  = lane & 15;

    const int srow = tid >> 2;
    const int scol = (tid & 3) * 8;

    f32x4 acc[4] = {};

    float4 a0 = *(const float4*)&A[(size_t)(bm + srow) * DM + scol];
    float4 a1 = *(const float4*)&A[(size_t)(bm + srow) * DM + scol + 4];
    float4 w0 = *(const float4*)&W[(size_t)(bn + srow) * DM + scol];
    float4 w1 = *(const float4*)&W[(size_t)(bn + srow) * DM + scol + 4];

    for (int k0 = 0; k0 < DM; k0 += 32) {
        bf16x8 ap, wp;
        ap[0] = f2bs(a0.x); ap[1] = f2bs(a0.y); ap[2] = f2bs(a0.z); ap[3] = f2bs(a0.w);
        ap[4] = f2bs(a1.x); ap[5] = f2bs(a1.y); ap[6] = f2bs(a1.z); ap[7] = f2bs(a1.w);
        wp[0] = f2bs(w0.x); wp[1] = f2bs(w0.y); wp[2] = f2bs(w0.z); wp[3] = f2bs(w0.w);
        wp[4] = f2bs(w1.x); wp[5] = f2bs(w1.y); wp[6] = f2bs(w1.z); wp[7] = f2bs(w1.w);

        __syncthreads();
        *(bf16x8*)&As[srow * 32 + scol] = ap;
        *(bf16x8*)&Ws[srow * 32 + scol] = wp;
        __syncthreads();

        if (k0 + 32 < DM) {
            a0 = *(const float4*)&A[(size_t)(bm + srow) * DM + k0 + 32 + scol];
            a1 = *(const float4*)&A[(size_t)(bm + srow) * DM + k0 + 32 + scol + 4];
            w0 = *(const float4*)&W[(size_t)(bn + srow) * DM + k0 + 32 + scol];
            w1 = *(const float4*)&W[(size_t)(bn + srow) * DM + k0 + 32 + scol + 4];
        }

        bf16x8 a = *(bf16x8*)&As[(wave * 16 + l16) * 32 + quad * 8];
#pragma unroll
        for (int nt = 0; nt < 4; nt++) {
            bf16x8 b = *(bf16x8*)&Ws[(nt * 16 + l16) * 32 + quad * 8];
            acc[nt] = __builtin_amdgcn_mfma_f32_16x16x32_bf16(a, b, acc[nt], 0, 0, 0);
        }
    }

    // C/D layout: col = lane&15, row = quad*4 + r
    if (z == 2) {
        const int row0 = bm + wave * 16 + quad * 4;
        const int b    = row0 >> 12;
        const int seq0 = row0 & 4095;
#pragma unroll
        for (int nt = 0; nt < 4; nt++) {
            const int col = bn + nt * 16 + l16;
            const float bv_ = bias[col];
            ushort4 pk;
            pk.x = (unsigned short)f2bs(acc[nt][0] + bv_);
            pk.y = (unsigned short)f2bs(acc[nt][1] + bv_);
            pk.z = (unsigned short)f2bs(acc[nt][2] + bv_);
            pk.w = (unsigned short)f2bs(acc[nt][3] + bv_);
            *(ushort4*)&((unsigned short*)Ovt)[((size_t)(b * 512 + col)) * 4096 + seq0] = pk;
        }
    } else {
        __hip_bfloat16* C = (z == 0) ? Oq : Ok;
#pragma unroll
        for (int nt = 0; nt < 4; nt++) {
            const int col = bn + nt * 16 + l16;
            const float bv_ = bias[col];
#pragma unroll
            for (int r = 0; r < 4; r++) {
                const int row = bm + wave * 16 + quad * 4 + r;
                C[(size_t)row * DM + col] = (__hip_bfloat16)((acc[nt][r] + bv_) * scale);
            }
        }
    }
}

// Flash attention. Q pre-scaled by 1/sqrt(dk). V supplied transposed per-head [bh][64][SEQ].
__global__ __launch_bounds__(256) void flash_attn(
    const __hip_bfloat16* __restrict__ Q,
    const __hip_bfloat16* __restrict__ K,
    const __hip_bfloat16* __restrict__ Vt,
    __hip_bfloat16* __restrict__ O)
{
    __shared__ __align__(16) short Qs[64 * FPAD];
    __shared__ __align__(16) short Ks[64 * FPAD];
    __shared__ __align__(16) short Vs[64 * FPAD];      // [dv][kv], pre-transposed
    __shared__ __align__(16) short Ps[4][16 * FPAD];   // per-wave P strip (no barrier needed)

    const int q0 = blockIdx.x * 64;
    const int bh = blockIdx.y;

    const int tid  = threadIdx.x;
    const int wave = tid >> 6;
    const int lane = tid & 63;
    const int quad = lane >> 4;
    const int l16  = lane & 15;

    const __hip_bfloat16* Qb = Q + (size_t)(bh >> 3) * SEQ * DM + (bh & 7) * 64;
    const __hip_bfloat16* Kb = K + (size_t)(bh >> 3) * SEQ * DM + (bh & 7) * 64;
    const __hip_bfloat16* Vb = Vt + (size_t)bh * 64 * SEQ;
    __hip_bfloat16*       Ob = O + (size_t)(bh >> 3) * SEQ * DM + (bh & 7) * 64;

    const int r0 = tid >> 3;        // 0..31 (covers rows r0 and r0+32)
    const int c8 = (tid & 7) * 8;

    *(bf16x8*)&Qs[r0 * FPAD + c8] =
        *(const bf16x8*)&Qb[(size_t)(q0 + r0) * DM + c8];
    *(bf16x8*)&Qs[(r0 + 32) * FPAD + c8] =
        *(const bf16x8*)&Qb[(size_t)(q0 + r0 + 32) * DM + c8];

    bf16x8 kp0 = *(const bf16x8*)&Kb[(size_t)r0 * DM + c8];
    bf16x8 kp1 = *(const bf16x8*)&Kb[(size_t)(r0 + 32) * DM + c8];
    bf16x8 vp0 = *(const bf16x8*)&Vb[(size_t)r0 * SEQ + c8];
    bf16x8 vp1 = *(const bf16x8*)&Vb[(size_t)(r0 + 32) * SEQ + c8];

    // ones B-fragment for the denominator MFMA (bf16 1.0 = 0x3F80)
    bf16x8 ones;
#pragma unroll
    for (int j = 0; j < 8; j++) ones[j] = (short)0x3F80;

    float m_run = -3.0e38f;
    f32x4 oacc[4] = {};
    f32x4 lacc = {};                 // row-sum accumulator; lacc[r] = l for row quad*4+r

    for (int kv0 = 0; kv0 < SEQ; kv0 += 64) {
        __syncthreads();   // prev PV done reading Ks/Vs (iter 0: orders Qs stage)
        *(bf16x8*)&Ks[r0 * FPAD + c8] = kp0;
        *(bf16x8*)&Ks[(r0 + 32) * FPAD + c8] = kp1;
        *(bf16x8*)&Vs[r0 * FPAD + c8] = vp0;
        *(bf16x8*)&Vs[(r0 + 32) * FPAD + c8] = vp1;
        __syncthreads();

        if (kv0 + 64 < SEQ) {   // prefetch next tile; overlaps softmax + PV
            kp0 = *(const bf16x8*)&Kb[(size_t)(kv0 + 64 + r0) * DM + c8];
            kp1 = *(const bf16x8*)&Kb[(size_t)(kv0 + 96 + r0) * DM + c8];
            vp0 = *(const bf16x8*)&Vb[(size_t)r0 * SEQ + kv0 + 64 + c8];
            vp1 = *(const bf16x8*)&Vb[(size_t)(r0 + 32) * SEQ + kv0 + 64 + c8];
        }

        // S = Q K^T (Q pre-scaled)
        f32x4 s[4] = {};
#pragma unroll
        for (int ks = 0; ks < 2; ks++) {
            bf16x8 a = *(bf16x8*)&Qs[(wave * 16 + l16) * FPAD + ks * 32 + quad * 8];
#pragma unroll
            for (int nt = 0; nt < 4; nt++) {
                bf16x8 b = *(bf16x8*)&Ks[(nt * 16 + l16) * FPAD + ks * 32 + quad * 8];
                s[nt] = __builtin_amdgcn_mfma_f32_16x16x32_bf16(a, b, s[nt], 0, 0, 0);
            }
        }

        // wave-global running max (upper-bounds every row; exact for online softmax)
        float mx = s[0][0];
#pragma unroll
        for (int nt = 0; nt < 4; nt++)
#pragma unroll
            for (int r = 0; r < 4; r++) mx = fmaxf(mx, s[nt][r]);
#pragma unroll
        for (int off = 1; off < 64; off <<= 1)
            mx = fmaxf(mx, __shfl_xor(mx, off, 64));

        const float mnew  = fmaxf(m_run, mx);
        const float alpha = safe_exp(m_run - mnew);
        m_run = mnew;

        // P = exp(S - m), written to per-wave LDS strip (A-operand layout source)
#pragma unroll
        for (int nt = 0; nt < 4; nt++) {
#pragma unroll
            for (int r = 0; r < 4; r++) {
                float p = safe_exp(s[nt][r] - mnew);
                Ps[wave][(quad * 4 + r) * FPAD + nt * 16 + l16] = f2bs(p);
            }
        }

        // rescale accumulators (lacc rides along: l_new = alpha*l_old + rowsum(P))
#pragma unroll
        for (int dt = 0; dt < 4; dt++)
#pragma unroll
            for (int r = 0; r < 4; r++) oacc[dt][r] *= alpha;
#pragma unroll
        for (int r = 0; r < 4; r++) lacc[r] *= alpha;

        // O += P @ V; l += P @ ones   (no barrier: Ps is per-wave, lgkmcnt orders it)
#pragma unroll
        for (int ks = 0; ks < 2; ks++) {
            bf16x8 a = *(bf16x8*)&Ps[wave][l16 * FPAD + ks * 32 + quad * 8];
#pragma unroll
            for (int dt = 0; dt < 4; dt++) {
                bf16x8 b = *(bf16x8*)&Vs[(dt * 16 + l16) * FPAD + ks * 32 + quad * 8];
                oacc[dt] = __builtin_amdgcn_mfma_f32_16x16x32_bf16(a, b, oacc[dt], 0, 0, 0);
            }
            lacc = __builtin_amdgcn_mfma_f32_16x16x32_bf16(a, ones, lacc, 0, 0, 0);
        }
    }

    // epilogue: O / l   (lacc[r] > 0: p >= exp(-60))
#pragma unroll
    for (int dt = 0; dt < 4; dt++) {
#pragma unroll
        for (int r = 0; r < 4; r++) {
            const int row = q0 + wave * 16 + quad * 4 + r;
            Ob[(size_t)row * DM + dt * 16 + l16] =
                (__hip_bfloat16)(oacc[dt][r] / lacc[r]);
        }
    }
}

// Output projection: A bf16 [8192][512], W/bias fp32, C fp32.
__global__ __launch_bounds__(256) void out_proj(
    const __hip_bfloat16* __restrict__ A,
    const float* __restrict__ W,
    const float* __restrict__ bias,
    float* __restrict__ C)
{
    __shared__ __align__(16) short As[64 * 32];
    __shared__ __align__(16) short Ws[64 * 32];

    const int bm   = blockIdx.x * 64;
    const int bn   = blockIdx.y * 64;
    const int tid  = threadIdx.x;
    const int wave = tid >> 6;
    const int lane = tid & 63;
    const int quad = lane >> 4;
    const int l16  = lane & 15;

    const int srow = tid >> 2;
    const int scol = (tid & 3) * 8;

    f32x4 acc[4] = {};

    bf16x8 ap = *(const bf16x8*)&A[(size_t)(bm + srow) * DM + scol];
    float4 w0 = *(const float4*)&W[(size_t)(bn + srow) * DM + scol];
    float4 w1 = *(const float4*)&W[(size_t)(bn + srow) * DM + scol + 4];

    for (int k0 = 0; k0 < DM; k0 += 32) {
        bf16x8 wp;
        wp[0] = f2bs(w0.x); wp[1] = f2bs(w0.y); wp[2] = f2bs(w0.z); wp[3] = f2bs(w0.w);
        wp[4] = f2bs(w1.x); wp[5] = f2bs(w1.y); wp[6] = f2bs(w1.z); wp[7] = f2bs(w1.w);

        __syncthreads();
        *(bf16x8*)&As[srow * 32 + scol] = ap;
        *(bf16x8*)&Ws[srow * 32 + scol] = wp;
        __syncthreads();

        if (k0 + 32 < DM) {
            ap = *(const bf16x8*)&A[(size_t)(bm + srow) * DM + k0 + 32 + scol];
            w0 = *(const float4*)&W[(size_t)(bn + srow) * DM + k0 + 32 + scol];
            w1 = *(const float4*)&W[(size_t)(bn + srow) * DM + k0 + 32 + scol + 4];
        }

        bf16x8 a = *(bf16x8*)&As[(wave * 16 + l16) * 32 + quad * 8];
#pragma unroll
        for (int nt = 0; nt < 4; nt++) {
            bf16x8 b = *(bf16x8*)&Ws[(nt * 16 + l16) * 32 + quad * 8];
            acc[nt] = __builtin_amdgcn_mfma_f32_16x16x32_bf16(a, b, acc[nt], 0, 0, 0);
        }
    }

#pragma unroll
    for (int nt = 0; nt < 4; nt++) {
        const int col = bn + nt * 16 + l16;
        const float bv_ = bias[col];
#pragma unroll
        for (int r = 0; r < 4; r++) {
            const int row = bm + wave * 16 + quad * 4 + r;
            C[(size_t)row * DM + col] = acc[nt][r] + bv_;
        }
    }
}

extern "C" void kernel_launch(void* const* d_in, const int* in_sizes, int n_in,
                              void* d_out, int out_size, void* d_ws, size_t ws_size,
                              hipStream_t stream) {
    const float* queries = (const float*)d_in[0];
    const float* keys    = (const float*)d_in[1];
    const float* values  = (const float*)d_in[2];
    const float* Wq = (const float*)d_in[3];
    const float* bq = (const float*)d_in[4];
    const float* Wk = (const float*)d_in[5];
    const float* bk = (const float*)d_in[6];
    const float* Wv = (const float*)d_in[7];
    const float* bv = (const float*)d_in[8];
    const float* Wo = (const float*)d_in[9];
    const float* bo = (const float*)d_in[10];
    float* out = (float*)d_out;

    const size_t MS = (size_t)2 * SEQ * DM;
    __hip_bfloat16* q_ws  = (__hip_bfloat16*)d_ws;
    __hip_bfloat16* k_ws  = q_ws + MS;
    __hip_bfloat16* vt_ws = k_ws + MS;    // [16][64][4096]
    __hip_bfloat16* o_ws  = vt_ws + MS;

    dim3 blk(256);

    qkv_proj<<<dim3(128, 8, 3), blk, 0, stream>>>(
        queries, keys, values, Wq, Wk, Wv, bq, bk, bv, q_ws, k_ws, vt_ws);

    flash_attn<<<dim3(64, 16), blk, 0, stream>>>(q_ws, k_ws, vt_ws, o_ws);

    out_proj<<<dim3(128, 8), blk, 0, stream>>>(o_ws, Wo, bo, out);
}

// Round 6
// 292.902 us; speedup vs baseline: 1.8482x; 1.0859x over previous
//
#include <hip/hip_runtime.h>
#include <hip/hip_bf16.h>

// MHA: fused qkv proj (V written transposed per-head) -> flash attention -> out proj.
// R6: flash restructured to transposed-S form: S^T = K·Q^T, O^T = V^T·P^T
// (operand-swap; identical LDS read patterns, transposed outputs). Each lane
// owns one q-row -> in-lane softmax (2 shuffles), P written as b64 (kills the
// 2.1e7 bank conflicts), vectorized O epilogue, Q-frags hoisted out of kv-loop.

typedef __attribute__((ext_vector_type(8))) short bf16x8;   // 8 bf16 (MFMA A/B frag)
typedef __attribute__((ext_vector_type(4))) float f32x4;    // MFMA C/D frag

#define SEQ  4096
#define DM   512
#define FPAD 72    // LDS row stride (shorts): 8-lane/4-bank-window = min-phase b128 reads

__device__ inline short f2bs(float x) {
    __hip_bfloat16 b = (__hip_bfloat16)x;   // RNE
    return *(short*)&b;
}

__device__ inline float safe_exp(float arg) {
    return __expf(fmaxf(arg, -60.0f));   // never Inf, never exactly 0
}

// Fused QKV projection. z = blockIdx.z selects stream:
//   z=0: Q = (x@Wq^T + bq) * 0.125  -> row-major bf16 [8192][512] (1/sqrt(dk) folded)
//   z=1: K                          -> row-major bf16 [8192][512]
//   z=2: V                          -> transposed per-head: out[(b*512+col)*4096 + seq]
__global__ __launch_bounds__(256) void qkv_proj(
    const float* __restrict__ Xq, const float* __restrict__ Xk, const float* __restrict__ Xv,
    const float* __restrict__ Wq, const float* __restrict__ Wk, const float* __restrict__ Wv,
    const float* __restrict__ bq, const float* __restrict__ bk, const float* __restrict__ bv,
    __hip_bfloat16* __restrict__ Oq, __hip_bfloat16* __restrict__ Ok,
    __hip_bfloat16* __restrict__ Ovt)
{
    const int z = blockIdx.z;
    const float* A    = (z == 0) ? Xq : (z == 1) ? Xk : Xv;
    const float* W    = (z == 0) ? Wq : (z == 1) ? Wk : Wv;
    const float* bias = (z == 0) ? bq : (z == 1) ? bk : bv;
    const float scale = (z == 0) ? 0.125f : 1.0f;

    __shared__ __align__(16) short As[64 * 32];   // 64B rows: conflict-free
    __shared__ __align__(16) short Ws[64 * 32];

    const int bm   = blockIdx.x * 64;
    const int bn   = blockIdx.y * 64;
    const int tid  = threadIdx.x;
    const int wave = tid >> 6;
    const int lane = tid & 63;
    const int quad = lane >> 4;
    const int l16  = lane & 15;

    const int srow = tid >> 2;
    const int scol = (tid & 3) * 8;

    f32x4 acc[4] = {};

    float4 a0 = *(const float4*)&A[(size_t)(bm + srow) * DM + scol];
    float4 a1 = *(const float4*)&A[(size_t)(bm + srow) * DM + scol + 4];
    float4 w0 = *(const float4*)&W[(size_t)(bn + srow) * DM + scol];
    float4 w1 = *(const float4*)&W[(size_t)(bn + srow) * DM + scol + 4];

    for (int k0 = 0; k0 < DM; k0 += 32) {
        bf16x8 ap, wp;
        ap[0] = f2bs(a0.x); ap[1] = f2bs(a0.y); ap[2] = f2bs(a0.z); ap[3] = f2bs(a0.w);
        ap[4] = f2bs(a1.x); ap[5] = f2bs(a1.y); ap[6] = f2bs(a1.z); ap[7] = f2bs(a1.w);
        wp[0] = f2bs(w0.x); wp[1] = f2bs(w0.y); wp[2] = f2bs(w0.z); wp[3] = f2bs(w0.w);
        wp[4] = f2bs(w1.x); wp[5] = f2bs(w1.y); wp[6] = f2bs(w1.z); wp[7] = f2bs(w1.w);

        __syncthreads();
        *(bf16x8*)&As[srow * 32 + scol] = ap;
        *(bf16x8*)&Ws[srow * 32 + scol] = wp;
        __syncthreads();

        if (k0 + 32 < DM) {
            a0 = *(const float4*)&A[(size_t)(bm + srow) * DM + k0 + 32 + scol];
            a1 = *(const float4*)&A[(size_t)(bm + srow) * DM + k0 + 32 + scol + 4];
            w0 = *(const float4*)&W[(size_t)(bn + srow) * DM + k0 + 32 + scol];
            w1 = *(const float4*)&W[(size_t)(bn + srow) * DM + k0 + 32 + scol + 4];
        }

        bf16x8 a = *(bf16x8*)&As[(wave * 16 + l16) * 32 + quad * 8];
#pragma unroll
        for (int nt = 0; nt < 4; nt++) {
            bf16x8 b = *(bf16x8*)&Ws[(nt * 16 + l16) * 32 + quad * 8];
            acc[nt] = __builtin_amdgcn_mfma_f32_16x16x32_bf16(a, b, acc[nt], 0, 0, 0);
        }
    }

    // C/D layout: col = lane&15 (= n), row = quad*4 + r (= m)
    if (z == 2) {
        const int row0 = bm + wave * 16 + quad * 4;
        const int b    = row0 >> 12;
        const int seq0 = row0 & 4095;
#pragma unroll
        for (int nt = 0; nt < 4; nt++) {
            const int col = bn + nt * 16 + l16;
            const float bv_ = bias[col];
            ushort4 pk;
            pk.x = (unsigned short)f2bs(acc[nt][0] + bv_);
            pk.y = (unsigned short)f2bs(acc[nt][1] + bv_);
            pk.z = (unsigned short)f2bs(acc[nt][2] + bv_);
            pk.w = (unsigned short)f2bs(acc[nt][3] + bv_);
            *(ushort4*)&((unsigned short*)Ovt)[((size_t)(b * 512 + col)) * 4096 + seq0] = pk;
        }
    } else {
        __hip_bfloat16* C = (z == 0) ? Oq : Ok;
#pragma unroll
        for (int nt = 0; nt < 4; nt++) {
            const int col = bn + nt * 16 + l16;
            const float bv_ = bias[col];
#pragma unroll
            for (int r = 0; r < 4; r++) {
                const int row = bm + wave * 16 + quad * 4 + r;
                C[(size_t)row * DM + col] = (__hip_bfloat16)((acc[nt][r] + bv_) * scale);
            }
        }
    }
}

// Flash attention, transposed-S form. Q pre-scaled by 1/sqrt(dk).
// V supplied transposed per-head [bh][64][SEQ].
// Block: one (bh, 64 q-rows); wave owns q = q0 + wave*16 + l16 (one q per lane).
__global__ __launch_bounds__(256) void flash_attn(
    const __hip_bfloat16* __restrict__ Q,
    const __hip_bfloat16* __restrict__ K,
    const __hip_bfloat16* __restrict__ Vt,
    __hip_bfloat16* __restrict__ O)
{
    __shared__ __align__(16) short Qs[64 * FPAD];      // [q][d]
    __shared__ __align__(16) short Ks[64 * FPAD];      // [kv][d]
    __shared__ __align__(16) short Vs[64 * FPAD];      // [dv][kv] (pre-transposed)
    __shared__ __align__(16) short Ps[4][16 * FPAD];   // per-wave: [q_local][kv]

    const int q0 = blockIdx.x * 64;
    const int bh = blockIdx.y;

    const int tid  = threadIdx.x;
    const int wave = tid >> 6;
    const int lane = tid & 63;
    const int quad = lane >> 4;
    const int l16  = lane & 15;

    const __hip_bfloat16* Qb = Q + (size_t)(bh >> 3) * SEQ * DM + (bh & 7) * 64;
    const __hip_bfloat16* Kb = K + (size_t)(bh >> 3) * SEQ * DM + (bh & 7) * 64;
    const __hip_bfloat16* Vb = Vt + (size_t)bh * 64 * SEQ;
    __hip_bfloat16*       Ob = O + (size_t)(bh >> 3) * SEQ * DM + (bh & 7) * 64;

    const int r0 = tid >> 3;        // 0..31 (covers rows r0 and r0+32)
    const int c8 = (tid & 7) * 8;

    // Q stage (once)
    *(bf16x8*)&Qs[r0 * FPAD + c8] =
        *(const bf16x8*)&Qb[(size_t)(q0 + r0) * DM + c8];
    *(bf16x8*)&Qs[(r0 + 32) * FPAD + c8] =
        *(const bf16x8*)&Qb[(size_t)(q0 + r0 + 32) * DM + c8];

    // prefetch kv tile 0
    bf16x8 kp0 = *(const bf16x8*)&Kb[(size_t)r0 * DM + c8];
    bf16x8 kp1 = *(const bf16x8*)&Kb[(size_t)(r0 + 32) * DM + c8];
    bf16x8 vp0 = *(const bf16x8*)&Vb[(size_t)r0 * SEQ + c8];
    bf16x8 vp1 = *(const bf16x8*)&Vb[(size_t)(r0 + 32) * SEQ + c8];

    __syncthreads();   // Qs staged

    // hoist loop-invariant Q B-frags (lane n = l16 -> q = wave*16+l16)
    const bf16x8 bq0 = *(bf16x8*)&Qs[(wave * 16 + l16) * FPAD + quad * 8];
    const bf16x8 bq1 = *(bf16x8*)&Qs[(wave * 16 + l16) * FPAD + 32 + quad * 8];

    float m_run = -3.0e38f;
    float l_run = 0.0f;
    f32x4 oacc[4] = {};   // O^T: lane holds (dv = dt*16+quad*4+r, q = l16)

    for (int kv0 = 0; kv0 < SEQ; kv0 += 64) {
        __syncthreads();   // prev PV done reading Ks/Vs
        *(bf16x8*)&Ks[r0 * FPAD + c8] = kp0;
        *(bf16x8*)&Ks[(r0 + 32) * FPAD + c8] = kp1;
        *(bf16x8*)&Vs[r0 * FPAD + c8] = vp0;
        *(bf16x8*)&Vs[(r0 + 32) * FPAD + c8] = vp1;
        __syncthreads();

        if (kv0 + 64 < SEQ) {   // prefetch next tile; overlaps softmax + PV
            kp0 = *(const bf16x8*)&Kb[(size_t)(kv0 + 64 + r0) * DM + c8];
            kp1 = *(const bf16x8*)&Kb[(size_t)(kv0 + 96 + r0) * DM + c8];
            vp0 = *(const bf16x8*)&Vb[(size_t)r0 * SEQ + kv0 + 64 + c8];
            vp1 = *(const bf16x8*)&Vb[(size_t)(r0 + 32) * SEQ + kv0 + 64 + c8];
        }

        // S^T = K Q^T: A = K-frag (m=kv), B = Q-frag (n=q)
        // s[nt] element r: (kv = nt*16 + quad*4 + r, q = l16)
        f32x4 s[4] = {};
#pragma unroll
        for (int nt = 0; nt < 4; nt++) {
            bf16x8 ak = *(bf16x8*)&Ks[(nt * 16 + l16) * FPAD + quad * 8];
            s[nt] = __builtin_amdgcn_mfma_f32_16x16x32_bf16(ak, bq0, s[nt], 0, 0, 0);
        }
#pragma unroll
        for (int nt = 0; nt < 4; nt++) {
            bf16x8 ak = *(bf16x8*)&Ks[(nt * 16 + l16) * FPAD + 32 + quad * 8];
            s[nt] = __builtin_amdgcn_mfma_f32_16x16x32_bf16(ak, bq1, s[nt], 0, 0, 0);
        }

        // per-q (per-lane) max: in-lane 16 + cross-quad (lanes sharing l16)
        float mx = fmaxf(fmaxf(s[0][0], s[0][1]), fmaxf(s[0][2], s[0][3]));
#pragma unroll
        for (int nt = 1; nt < 4; nt++)
#pragma unroll
            for (int r = 0; r < 4; r++) mx = fmaxf(mx, s[nt][r]);
        mx = fmaxf(mx, __shfl_xor(mx, 16, 64));
        mx = fmaxf(mx, __shfl_xor(mx, 32, 64));

        const float mnew  = fmaxf(m_run, mx);
        const float alpha = safe_exp(m_run - mnew);
        m_run = mnew;

        // P = exp(S - m): pack 4 consecutive kv -> one b64 write per nt
        float rs = 0.0f;
#pragma unroll
        for (int nt = 0; nt < 4; nt++) {
            float p0 = safe_exp(s[nt][0] - mnew);
            float p1 = safe_exp(s[nt][1] - mnew);
            float p2 = safe_exp(s[nt][2] - mnew);
            float p3 = safe_exp(s[nt][3] - mnew);
            rs += (p0 + p1) + (p2 + p3);
            ushort4 pk;
            pk.x = (unsigned short)f2bs(p0);
            pk.y = (unsigned short)f2bs(p1);
            pk.z = (unsigned short)f2bs(p2);
            pk.w = (unsigned short)f2bs(p3);
            *(ushort4*)&Ps[wave][l16 * FPAD + nt * 16 + quad * 4] = pk;
        }
        rs += __shfl_xor(rs, 16, 64);
        rs += __shfl_xor(rs, 32, 64);
        l_run = alpha * l_run + rs;

#pragma unroll
        for (int dt = 0; dt < 4; dt++)
#pragma unroll
            for (int r = 0; r < 4; r++) oacc[dt][r] *= alpha;

        // O^T += V^T P^T: A = V-frag (m=dv), B = P-frag (n=q)
        // (no barrier: Ps strip is per-wave; lgkmcnt orders same-wave DS ops)
#pragma unroll
        for (int ks = 0; ks < 2; ks++) {
            bf16x8 bp = *(bf16x8*)&Ps[wave][l16 * FPAD + ks * 32 + quad * 8];
#pragma unroll
            for (int dt = 0; dt < 4; dt++) {
                bf16x8 av = *(bf16x8*)&Vs[(dt * 16 + l16) * FPAD + ks * 32 + quad * 8];
                oacc[dt] = __builtin_amdgcn_mfma_f32_16x16x32_bf16(av, bp, oacc[dt], 0, 0, 0);
            }
        }
    }

    // epilogue: lane owns q = q0 + wave*16 + l16; O[q][dv], 4 consecutive dv per dt
    const float inv = 1.0f / l_run;
    const int q = q0 + wave * 16 + l16;
#pragma unroll
    for (int dt = 0; dt < 4; dt++) {
        ushort4 ov;
        ov.x = (unsigned short)f2bs(oacc[dt][0] * inv);
        ov.y = (unsigned short)f2bs(oacc[dt][1] * inv);
        ov.z = (unsigned short)f2bs(oacc[dt][2] * inv);
        ov.w = (unsigned short)f2bs(oacc[dt][3] * inv);
        *(ushort4*)&((unsigned short*)Ob)[(size_t)q * DM + dt * 16 + quad * 4] = ov;
    }
}

// Output projection: A bf16 [8192][512], W/bias fp32, C fp32.
__global__ __launch_bounds__(256) void out_proj(
    const __hip_bfloat16* __restrict__ A,
    const float* __restrict__ W,
    const float* __restrict__ bias,
    float* __restrict__ C)
{
    __shared__ __align__(16) short As[64 * 32];
    __shared__ __align__(16) short Ws[64 * 32];

    const int bm   = blockIdx.x * 64;
    const int bn   = blockIdx.y * 64;
    const int tid  = threadIdx.x;
    const int wave = tid >> 6;
    const int lane = tid & 63;
    const int quad = lane >> 4;
    const int l16  = lane & 15;

    const int srow = tid >> 2;
    const int scol = (tid & 3) * 8;

    f32x4 acc[4] = {};

    bf16x8 ap = *(const bf16x8*)&A[(size_t)(bm + srow) * DM + scol];
    float4 w0 = *(const float4*)&W[(size_t)(bn + srow) * DM + scol];
    float4 w1 = *(const float4*)&W[(size_t)(bn + srow) * DM + scol + 4];

    for (int k0 = 0; k0 < DM; k0 += 32) {
        bf16x8 wp;
        wp[0] = f2bs(w0.x); wp[1] = f2bs(w0.y); wp[2] = f2bs(w0.z); wp[3] = f2bs(w0.w);
        wp[4] = f2bs(w1.x); wp[5] = f2bs(w1.y); wp[6] = f2bs(w1.z); wp[7] = f2bs(w1.w);

        __syncthreads();
        *(bf16x8*)&As[srow * 32 + scol] = ap;
        *(bf16x8*)&Ws[srow * 32 + scol] = wp;
        __syncthreads();

        if (k0 + 32 < DM) {
            ap = *(const bf16x8*)&A[(size_t)(bm + srow) * DM + k0 + 32 + scol];
            w0 = *(const float4*)&W[(size_t)(bn + srow) * DM + k0 + 32 + scol];
            w1 = *(const float4*)&W[(size_t)(bn + srow) * DM + k0 + 32 + scol + 4];
        }

        bf16x8 a = *(bf16x8*)&As[(wave * 16 + l16) * 32 + quad * 8];
#pragma unroll
        for (int nt = 0; nt < 4; nt++) {
            bf16x8 b = *(bf16x8*)&Ws[(nt * 16 + l16) * 32 + quad * 8];
            acc[nt] = __builtin_amdgcn_mfma_f32_16x16x32_bf16(a, b, acc[nt], 0, 0, 0);
        }
    }

#pragma unroll
    for (int nt = 0; nt < 4; nt++) {
        const int col = bn + nt * 16 + l16;
        const float bv_ = bias[col];
#pragma unroll
        for (int r = 0; r < 4; r++) {
            const int row = bm + wave * 16 + quad * 4 + r;
            C[(size_t)row * DM + col] = acc[nt][r] + bv_;
        }
    }
}

extern "C" void kernel_launch(void* const* d_in, const int* in_sizes, int n_in,
                              void* d_out, int out_size, void* d_ws, size_t ws_size,
                              hipStream_t stream) {
    const float* queries = (const float*)d_in[0];
    const float* keys    = (const float*)d_in[1];
    const float* values  = (const float*)d_in[2];
    const float* Wq = (const float*)d_in[3];
    const float* bq = (const float*)d_in[4];
    const float* Wk = (const float*)d_in[5];
    const float* bk = (const float*)d_in[6];
    const float* Wv = (const float*)d_in[7];
    const float* bv = (const float*)d_in[8];
    const float* Wo = (const float*)d_in[9];
    const float* bo = (const float*)d_in[10];
    float* out = (float*)d_out;

    const size_t MS = (size_t)2 * SEQ * DM;
    __hip_bfloat16* q_ws  = (__hip_bfloat16*)d_ws;
    __hip_bfloat16* k_ws  = q_ws + MS;
    __hip_bfloat16* vt_ws = k_ws + MS;    // [16][64][4096]
    __hip_bfloat16* o_ws  = vt_ws + MS;

    dim3 blk(256);

    qkv_proj<<<dim3(128, 8, 3), blk, 0, stream>>>(
        queries, keys, values, Wq, Wk, Wv, bq, bk, bv, q_ws, k_ws, vt_ws);

    flash_attn<<<dim3(64, 16), blk, 0, stream>>>(q_ws, k_ws, vt_ws, o_ws);

    out_proj<<<dim3(128, 8), blk, 0, stream>>>(o_ws, Wo, bo, out);
}